// Round 13
// baseline (149.595 us; speedup 1.0000x reference)
//
#include <hip/hip_runtime.h>

// FeaturePropagationV2: 3-NN inverse-distance interpolation + Linear, fused as:
//   G = feature2 @ W.T          (precomputed once, 8192x256)
//   out[i] = sum_k w_k * G[idx_k] + b
//
// kNN, TWO queries per lane (block = 128 queries, 256 blocks = 1/CU), full
// 8192-pt cloud resident in LDS (128 KB, single stage). Each broadcast
// ds_read_b128 serves 64 lanes x 2 queries -> half the DS traffic of r11.
//   Phase 1: first 256 pts of wave's range, sloppy batch-min top-4 -> thr.
//   Phase 2: wave scans its 1024-pt range for both query sets; threshold
//            folded into the FMA chain (acc = dot + t, survive iff acc>=pw).
//   Select : exact reference-f32 re-score, stable (d2,idx) top-3.
//            *** Overflowed cells (raw cnt > CAP, ring incomplete) fall back
//            to an exact full-range rescan from global — correctness is
//            CAP-independent (r12 failed on ring-overflow tail: survivor
//            count ~ Gamma(4), not Poisson; CAP=12 -> ~1-2 bad queries). ***
// LDS 161.5 KB: slab_raw <- mdl/mil (stage A, slab dead);
//               ring_raw <- mdl4 (phase 1), swgt/sidx (stage B, ring dead).

#define FLT_BIG 3.402823466e+38f
#define CAP     14
#define RROW    (8 * CAP + 1)     // 113 u16 = 226 B row, bank-spread
#define MARGIN  3e-5f

__global__ __launch_bounds__(256) void prep_kernel(const float* __restrict__ xyz2,
                                                   float4* __restrict__ pack, int N2) {
    int j = blockIdx.x * 256 + threadIdx.x;
    if (j < N2) {
        float x = xyz2[3 * j + 0];
        float y = xyz2[3 * j + 1];
        float z = xyz2[3 * j + 2];
        float4 p;
        p.x = x; p.y = y; p.z = z;
        p.w = 0.5f * (x * x + y * y + z * z);   // scan metric only
        pack[j] = p;
    }
}

// C[m][n] = sum_k A[m][k] * B[n][k]   (unchanged)
__global__ __launch_bounds__(256) void gemm_nt_f32(const float* __restrict__ A,
                                                   const float* __restrict__ B,
                                                   float* __restrict__ C,
                                                   int M, int N, int K) {
    __shared__ float As[64][68];
    __shared__ float Bs[64][68];

    const int t  = threadIdx.x;
    const int tx = t & 15;
    const int ty = t >> 4;
    const int bm = blockIdx.x * 64;
    const int bn = blockIdx.y * 64;

    float acc[4][4] = {{0.f}};

    for (int kt = 0; kt < K; kt += 64) {
#pragma unroll
        for (int rr = 0; rr < 4; ++rr) {
            int r = ty + 16 * rr;
            int c = tx * 4;
            float4 av = *(const float4*)(A + (size_t)(bm + r) * K + kt + c);
            As[c + 0][r] = av.x;
            As[c + 1][r] = av.y;
            As[c + 2][r] = av.z;
            As[c + 3][r] = av.w;
            float4 bv = *(const float4*)(B + (size_t)(bn + r) * K + kt + c);
            Bs[c + 0][r] = bv.x;
            Bs[c + 1][r] = bv.y;
            Bs[c + 2][r] = bv.z;
            Bs[c + 3][r] = bv.w;
        }
        __syncthreads();

#pragma unroll 8
        for (int k = 0; k < 64; ++k) {
            float4 a4 = *(const float4*)&As[k][ty * 4];
            float4 b4 = *(const float4*)&Bs[k][tx * 4];
            float a[4] = {a4.x, a4.y, a4.z, a4.w};
            float b[4] = {b4.x, b4.y, b4.z, b4.w};
#pragma unroll
            for (int i = 0; i < 4; ++i)
#pragma unroll
                for (int j = 0; j < 4; ++j)
                    acc[i][j] = fmaf(a[i], b[j], acc[i][j]);
        }
        __syncthreads();
    }

#pragma unroll
    for (int i = 0; i < 4; ++i) {
        float4 v;
        v.x = acc[i][0]; v.y = acc[i][1]; v.z = acc[i][2]; v.w = acc[i][3];
        *(float4*)(C + (size_t)(bm + ty * 4 + i) * N + bn + tx * 4) = v;
    }
}

// branchless value-only sorted top-4 insert: 7 min/max ops
#define TOP4V_INSERT(B0, B1, B2, B3, mv)                           \
    do {                                                           \
        float _x  = (mv);                                          \
        float _n0 = fminf(B0, _x);  float _y0 = fmaxf(B0, _x); B0 = _n0; \
        float _n1 = fminf(B1, _y0); float _y1 = fmaxf(B1, _y0); B1 = _n1; \
        float _n2 = fminf(B2, _y1); float _y2 = fmaxf(B2, _y1); B2 = _n2; \
        B3 = fminf(B3, _y2);                                       \
    } while (0)

// stable (dd, j) insert into sorted top-3 (d0<=d1<=d2v), idx tiebreak
#define TOP3JD_INSERT(dd, j)                                       \
    do {                                                           \
        bool lt2 = ((dd) < d2v) || ((dd) == d2v && (j) < j2);      \
        if (lt2) {                                                 \
            bool lt1 = ((dd) < d1) || ((dd) == d1 && (j) < j1);    \
            if (lt1) {                                             \
                d2v = d1; j2 = j1;                                 \
                bool lt0 = ((dd) < d0) || ((dd) == d0 && (j) < j0);\
                if (lt0) { d1 = d0; j1 = j0; d0 = (dd); j0 = (j); }\
                else     { d1 = (dd); j1 = (j); }                  \
            } else { d2v = (dd); j2 = (j); }                       \
        }                                                          \
    } while (0)

// exact reference-f32 d2 of pack point p vs query (sqx,sqy,sqz) with qsq
#define REF_D2(p)                                                              \
    __fsub_rn(__fadd_rn(qsq, __fadd_rn(__fadd_rn(__fmul_rn((p).x, (p).x),      \
                                                 __fmul_rn((p).y, (p).y)),     \
                                       __fmul_rn((p).z, (p).z))),              \
              __fmul_rn(2.0f, __fmaf_rn(sqz, (p).z,                            \
                                __fmaf_rn(sqy, (p).y, __fmul_rn(sqx, (p).x)))))

// Block: 512 threads = 8 waves, owns 128 fine points (2 queries per lane:
// qa = qbase+lane, qb = qbase+64+lane). Wave w scans [w*1024,(w+1)*1024)
// of the LDS-resident full cloud for both query sets.
__global__ __launch_bounds__(512) void knn_gather(const float* __restrict__ xyz1,
                                                  const float4* __restrict__ pack,
                                                  const float4* __restrict__ G4,    // [N2*64]
                                                  const float4* __restrict__ bias4, // [64]
                                                  float4* __restrict__ out4,        // [N1*64]
                                                  int N2) {
    // 131072 B: whole cloud; stage A (slab dead) reuses first 25600 B as
    // mdl[128][25] f32 + mil[128][25] i32.
    __shared__ __align__(16) unsigned char slab_raw[131072];
    // 28928 B: rings [128][RROW] u16; phase 1 reuses as mdl4[128][33] f32;
    // stage B (ring dead) reuses as swgt[128][3] f32 + sidx[128][3] i32.
    __shared__ __align__(16) unsigned char ring_raw[128 * RROW * 2];
    __shared__ float         thr[128];
    __shared__ unsigned char cnts[128][8];

    float4*         slab = (float4*)slab_raw;                    // [8192]
    float*          mdl  = (float*)slab_raw;                     // [128][25]
    int*            mil  = (int*)(slab_raw + 12800);             // [128][25]
    unsigned short* ring = (unsigned short*)ring_raw;            // [128][RROW]
    float*          mdl4 = (float*)ring_raw;                     // [128][33]
    float*          swgt = (float*)ring_raw;                     // [128][3]
    int*            sidx = (int*)(ring_raw + 1536);              // [128][3]

    const int tid   = threadIdx.x;
    const int wave  = __builtin_amdgcn_readfirstlane(tid >> 6);
    const int lane  = tid & 63;
    const int qbase = blockIdx.x * 128;

    const float qax = xyz1[3 * (qbase + lane) + 0];
    const float qay = xyz1[3 * (qbase + lane) + 1];
    const float qaz = xyz1[3 * (qbase + lane) + 2];
    const float qbx = xyz1[3 * (qbase + 64 + lane) + 0];
    const float qby = xyz1[3 * (qbase + 64 + lane) + 1];
    const float qbz = xyz1[3 * (qbase + 64 + lane) + 2];

    // ---- Stage the whole cloud into LDS (coalesced) ----
#pragma unroll 4
    for (int i = 0; i < 16; ++i) {
        int idx = i * 512 + tid;
        slab[idx] = pack[idx];
    }
    __syncthreads();

    // ---- Phase 1: batch-min(4) sloppy top-4 over first 256 of wave range
    {
        float a0 = FLT_BIG, a1 = FLT_BIG, a2 = FLT_BIG, a3 = FLT_BIG;
        float c0 = FLT_BIG, c1 = FLT_BIG, c2 = FLT_BIG, c3 = FLT_BIG;
        const float4* sp = slab + wave * 1024;
#pragma unroll 1
        for (int k = 0; k < 256; k += 4) {
            float4 p0 = sp[k + 0];              // uniform addr -> broadcast
            float4 p1 = sp[k + 1];
            float4 p2 = sp[k + 2];
            float4 p3 = sp[k + 3];
            float ma0 = p0.w - fmaf(qax, p0.x, fmaf(qay, p0.y, qaz * p0.z));
            float ma1 = p1.w - fmaf(qax, p1.x, fmaf(qay, p1.y, qaz * p1.z));
            float ma2 = p2.w - fmaf(qax, p2.x, fmaf(qay, p2.y, qaz * p2.z));
            float ma3 = p3.w - fmaf(qax, p3.x, fmaf(qay, p3.y, qaz * p3.z));
            float mma = fminf(fminf(ma0, ma1), fminf(ma2, ma3));
            TOP4V_INSERT(a0, a1, a2, a3, mma);  // batch-min under-maintains ->
            float mb0 = p0.w - fmaf(qbx, p0.x, fmaf(qby, p0.y, qbz * p0.z));
            float mb1 = p1.w - fmaf(qbx, p1.x, fmaf(qby, p1.y, qbz * p1.z));
            float mb2 = p2.w - fmaf(qbx, p2.x, fmaf(qby, p2.y, qbz * p2.z));
            float mb3 = p3.w - fmaf(qbx, p3.x, fmaf(qby, p3.y, qbz * p3.z));
            float mmb = fminf(fminf(mb0, mb1), fminf(mb2, mb3));
            TOP4V_INSERT(c0, c1, c2, c3, mmb);  // larger t (safe direction)
        }
        mdl4[lane * 33 + wave * 4 + 0] = a0;
        mdl4[lane * 33 + wave * 4 + 1] = a1;
        mdl4[lane * 33 + wave * 4 + 2] = a2;
        mdl4[lane * 33 + wave * 4 + 3] = a3;
        mdl4[(64 + lane) * 33 + wave * 4 + 0] = c0;
        mdl4[(64 + lane) * 33 + wave * 4 + 1] = c1;
        mdl4[(64 + lane) * 33 + wave * 4 + 2] = c2;
        mdl4[(64 + lane) * 33 + wave * 4 + 3] = c3;
    }
    __syncthreads();

    if (tid < 128) {
        float b0 = FLT_BIG, b1 = FLT_BIG, b2 = FLT_BIG, b3 = FLT_BIG;
#pragma unroll
        for (int w = 0; w < 8; ++w)
#pragma unroll
            for (int k = 0; k < 4; ++k)
                TOP4V_INSERT(b0, b1, b2, b3, mdl4[tid * 33 + w * 4 + k]);
        thr[tid] = b3 + MARGIN;   // sample-4th >= true-3rd; margin covers
    }                              // formula-rounding differences vs ref d2
    __syncthreads();

    // ---- Phase 2: scan wave's 1024 pts for both queries; threshold seeded
    //      into the fma chain: acc = dot + t, survive iff acc >= pw ----
    {
        const float ta = thr[lane];
        const float tb = thr[64 + lane];
        unsigned short* ringa = ring + lane * RROW + wave * CAP;
        unsigned short* ringb = ring + (64 + lane) * RROW + wave * CAP;
        int cnta = 0, cntb = 0;
        const float4* sp = slab + wave * 1024;
        const int gbase = wave * 1024;
#pragma unroll 1
        for (int jj = 0; jj < 1024; jj += 4) {
            float4 p0 = sp[jj + 0];             // uniform -> broadcast
            float4 p1 = sp[jj + 1];
            float4 p2 = sp[jj + 2];
            float4 p3 = sp[jj + 3];
            float aa0 = fmaf(qax, p0.x, fmaf(qay, p0.y, fmaf(qaz, p0.z, ta)));
            float aa1 = fmaf(qax, p1.x, fmaf(qay, p1.y, fmaf(qaz, p1.z, ta)));
            float aa2 = fmaf(qax, p2.x, fmaf(qay, p2.y, fmaf(qaz, p2.z, ta)));
            float aa3 = fmaf(qax, p3.x, fmaf(qay, p3.y, fmaf(qaz, p3.z, ta)));
            float ab0 = fmaf(qbx, p0.x, fmaf(qby, p0.y, fmaf(qbz, p0.z, tb)));
            float ab1 = fmaf(qbx, p1.x, fmaf(qby, p1.y, fmaf(qbz, p1.z, tb)));
            float ab2 = fmaf(qbx, p2.x, fmaf(qby, p2.y, fmaf(qbz, p2.z, tb)));
            float ab3 = fmaf(qbx, p3.x, fmaf(qby, p3.y, fmaf(qbz, p3.z, tb)));
            bool sa0 = aa0 >= p0.w, sa1 = aa1 >= p1.w;
            bool sa2 = aa2 >= p2.w, sa3 = aa3 >= p3.w;
            bool sb0 = ab0 >= p0.w, sb1 = ab1 >= p1.w;
            bool sb2 = ab2 >= p2.w, sb3 = ab3 >= p3.w;
            if (__any((sa0 | sa1 | sa2 | sa3) | (sb0 | sb1 | sb2 | sb3))) {
                if (sa0) { ringa[min(cnta, CAP - 1)] = (unsigned short)(gbase + jj + 0); ++cnta; }
                if (sa1) { ringa[min(cnta, CAP - 1)] = (unsigned short)(gbase + jj + 1); ++cnta; }
                if (sa2) { ringa[min(cnta, CAP - 1)] = (unsigned short)(gbase + jj + 2); ++cnta; }
                if (sa3) { ringa[min(cnta, CAP - 1)] = (unsigned short)(gbase + jj + 3); ++cnta; }
                if (sb0) { ringb[min(cntb, CAP - 1)] = (unsigned short)(gbase + jj + 0); ++cntb; }
                if (sb1) { ringb[min(cntb, CAP - 1)] = (unsigned short)(gbase + jj + 1); ++cntb; }
                if (sb2) { ringb[min(cntb, CAP - 1)] = (unsigned short)(gbase + jj + 2); ++cntb; }
                if (sb3) { ringb[min(cntb, CAP - 1)] = (unsigned short)(gbase + jj + 3); ++cntb; }
            }
        }
        cnts[lane][wave]      = (unsigned char)min(cnta, 255);  // RAW count
        cnts[64 + lane][wave] = (unsigned char)min(cntb, 255);  // (overflow flag)
    }
    __syncthreads();

    // ---- Selection stage A: 1024 tasks (q,w), 2 per thread; exact ref-f32
    //      re-score. Ring complete (raw <= CAP): score ring entries.
    //      Ring overflowed: exact fallback — rescan the cell's full 1024-pt
    //      range from global pack (slab is being overwritten by mdl/mil). ----
#pragma unroll
    for (int rep = 0; rep < 2; ++rep) {
        const int task = rep * 512 + tid;
        const int q  = task >> 3;
        const int w  = task & 7;
        const int fq = qbase + q;
        const float sqx = xyz1[3 * fq + 0];
        const float sqy = xyz1[3 * fq + 1];
        const float sqz = xyz1[3 * fq + 2];
        // q_sq = (qx*qx + qy*qy) + qz*qz  (no contraction, ref rounding)
        const float qsq = __fadd_rn(__fadd_rn(__fmul_rn(sqx, sqx), __fmul_rn(sqy, sqy)),
                                    __fmul_rn(sqz, sqz));
        float d0 = FLT_BIG, d1 = FLT_BIG, d2v = FLT_BIG;
        int   j0 = 0x7fffffff, j1 = 0x7fffffff, j2 = 0x7fffffff;
        const int rawn = (int)cnts[q][w];
        if (rawn <= CAP) {
#pragma unroll 1
            for (int e = 0; e < rawn; ++e) {
                const int j = ring[q * RROW + w * CAP + e];
                float4 p = pack[j];             // global; pack is L2-resident
                float dd = REF_D2(p);
                TOP3JD_INSERT(dd, j);
            }
        } else {
            // rare exact fallback (~1e-4 of cells): full cell range
            const int gb = w * 1024;
#pragma unroll 1
            for (int j = gb; j < gb + 1024; ++j) {
                float4 p = pack[j];
                float dd = REF_D2(p);
                TOP3JD_INSERT(dd, j);
            }
        }
        mdl[q * 25 + w * 3 + 0] = d0;  mdl[q * 25 + w * 3 + 1] = d1;  mdl[q * 25 + w * 3 + 2] = d2v;
        mil[q * 25 + w * 3 + 0] = j0;  mil[q * 25 + w * 3 + 1] = j1;  mil[q * 25 + w * 3 + 2] = j2;
        __syncthreads();   // uniform: both reps execute for all threads
    }

    // ---- Selection stage B: one thread per query merges 8x3, weights ----
    // (swgt/sidx alias ring_raw — ring is dead after stage A)
    if (tid < 128) {
        float d0 = FLT_BIG, d1 = FLT_BIG, d2v = FLT_BIG;
        int   j0 = 0x7fffffff, j1 = 0x7fffffff, j2 = 0x7fffffff;
#pragma unroll
        for (int w = 0; w < 8; ++w)
#pragma unroll
            for (int k = 0; k < 3; ++k) {
                float dd = mdl[tid * 25 + w * 3 + k];
                int   j  = mil[tid * 25 + w * 3 + k];
                TOP3JD_INSERT(dd, j);
            }
        // f32 inverse-distance weights, reference op order
        float w0 = 1.0f / (__fadd_rn(sqrtf(fmaxf(d0,  1e-12f)), 1e-8f));
        float w1 = 1.0f / (__fadd_rn(sqrtf(fmaxf(d1,  1e-12f)), 1e-8f));
        float w2 = 1.0f / (__fadd_rn(sqrtf(fmaxf(d2v, 1e-12f)), 1e-8f));
        float wsum = __fadd_rn(__fadd_rn(w0, w1), w2);
        swgt[tid * 3 + 0] = w0 / wsum; sidx[tid * 3 + 0] = j0;
        swgt[tid * 3 + 1] = w1 / wsum; sidx[tid * 3 + 1] = j1;
        swgt[tid * 3 + 2] = w2 / wsum; sidx[tid * 3 + 2] = j2;
    }
    __syncthreads();

    // ---- Gather: out[q] = w0*G[j0] + w1*G[j1] + w2*G[j2] + b (16 rows/wave)
    const float4 bb = bias4[lane];
#pragma unroll
    for (int p = 0; p < 16; ++p) {
        int row = wave * 16 + p;
        float w0 = swgt[row * 3 + 0];
        float w1 = swgt[row * 3 + 1];
        float w2 = swgt[row * 3 + 2];
        int j0 = sidx[row * 3 + 0];
        int j1 = sidx[row * 3 + 1];
        int j2 = sidx[row * 3 + 2];
        float4 g0 = G4[(size_t)j0 * 64 + lane];
        float4 g1 = G4[(size_t)j1 * 64 + lane];
        float4 g2 = G4[(size_t)j2 * 64 + lane];
        float4 o;
        o.x = fmaf(w0, g0.x, fmaf(w1, g1.x, fmaf(w2, g2.x, bb.x)));
        o.y = fmaf(w0, g0.y, fmaf(w1, g1.y, fmaf(w2, g2.y, bb.y)));
        o.z = fmaf(w0, g0.z, fmaf(w1, g1.z, fmaf(w2, g2.z, bb.z)));
        o.w = fmaf(w0, g0.w, fmaf(w1, g1.w, fmaf(w2, g2.w, bb.w)));
        out4[(size_t)(qbase + row) * 64 + lane] = o;
    }
}

extern "C" void kernel_launch(void* const* d_in, const int* in_sizes, int n_in,
                              void* d_out, int out_size, void* d_ws, size_t ws_size,
                              hipStream_t stream) {
    const float* xyz1 = (const float*)d_in[0];
    const float* xyz2 = (const float*)d_in[1];
    // d_in[2] = feature1 (unused by the reference computation)
    const float* f2   = (const float*)d_in[3];
    const float* W    = (const float*)d_in[6];
    const float* bias = (const float*)d_in[7];

    const int N1  = in_sizes[0] / 3;   // 32768
    const int N2  = in_sizes[1] / 3;   // 8192
    const int C   = in_sizes[3] / N2;  // 256
    const int OUT = in_sizes[7];       // 256

    float*  G    = (float*)d_ws;                                   // N2*OUT f32 = 8 MB
    float4* pack = (float4*)((char*)d_ws + (size_t)N2 * OUT * 4);  // N2 float4 = 128 KB

    prep_kernel<<<(N2 + 255) / 256, 256, 0, stream>>>(xyz2, pack, N2);

    dim3 ggrid(N2 / 64, OUT / 64);
    gemm_nt_f32<<<ggrid, 256, 0, stream>>>(f2, W, G, N2, OUT, C);

    knn_gather<<<N1 / 128, 512, 0, stream>>>(xyz1, pack, (const float4*)G,
                                             (const float4*)bias, (float4*)d_out, N2);
}

// Round 14
// 106.786 us; speedup vs baseline: 1.4009x; 1.4009x over previous
//
#include <hip/hip_runtime.h>

// FeaturePropagationV2: 3-NN inverse-distance interpolation + Linear, fused as:
//   G = feature2 @ W.T          (precomputed once, 8192x256)
//   out[i] = sum_k w_k * G[idx_k] + b
//
// kNN = r11 structure (validated best: 64 q/block, 8 waves, half-cloud LDS
// double-pass, 4 waves/SIMD) + PACKED-FP32 scan. Slab staged pair-interleaved
// ({x0,x1,y0,y1}{z0,z1,w0,w1} per 2 pts) so float2 ext-vector fma maps to
// v_pk_fma_f32 (2 pts per instr): filter = 3 pk_fma + 2 cmp per 2 points,
// threshold folded into the fma seed (acc = dot + t >= pw).
//   Phase 1: first 256 pts of wave's half-0 range, packed m, batch-min(4)
//            sloppy top-4 -> per-query threshold (+MARGIN).
//   Phase 2: two half-cloud passes, survivor push to per-(q,wave) rings,
//            RAW count stored; overflow -> exact fallback (r13-validated).
//   Select : exact reference-f32 re-score, stable (d2,idx) top-3 (validated).
// LDS 80.8 KB -> 2 blocks/CU. Aliases: slab <- mdl/mil (stage A, slab dead);
// ring <- mdl4 (phase 1), swgt/sidx (stage B, ring dead).

#define FLT_BIG 3.402823466e+38f
#define CAP     14
#define RROW    (8 * CAP + 1)     // 113 u16 = 226 B row, bank-spread
#define MARGIN  3e-5f

typedef float v2f __attribute__((ext_vector_type(2)));

__global__ __launch_bounds__(256) void prep_kernel(const float* __restrict__ xyz2,
                                                   float4* __restrict__ pack, int N2) {
    int j = blockIdx.x * 256 + threadIdx.x;
    if (j < N2) {
        float x = xyz2[3 * j + 0];
        float y = xyz2[3 * j + 1];
        float z = xyz2[3 * j + 2];
        float4 p;
        p.x = x; p.y = y; p.z = z;
        p.w = 0.5f * (x * x + y * y + z * z);   // scan metric only
        pack[j] = p;
    }
}

// C[m][n] = sum_k A[m][k] * B[n][k]   (unchanged)
__global__ __launch_bounds__(256) void gemm_nt_f32(const float* __restrict__ A,
                                                   const float* __restrict__ B,
                                                   float* __restrict__ C,
                                                   int M, int N, int K) {
    __shared__ float As[64][68];
    __shared__ float Bs[64][68];

    const int t  = threadIdx.x;
    const int tx = t & 15;
    const int ty = t >> 4;
    const int bm = blockIdx.x * 64;
    const int bn = blockIdx.y * 64;

    float acc[4][4] = {{0.f}};

    for (int kt = 0; kt < K; kt += 64) {
#pragma unroll
        for (int rr = 0; rr < 4; ++rr) {
            int r = ty + 16 * rr;
            int c = tx * 4;
            float4 av = *(const float4*)(A + (size_t)(bm + r) * K + kt + c);
            As[c + 0][r] = av.x;
            As[c + 1][r] = av.y;
            As[c + 2][r] = av.z;
            As[c + 3][r] = av.w;
            float4 bv = *(const float4*)(B + (size_t)(bn + r) * K + kt + c);
            Bs[c + 0][r] = bv.x;
            Bs[c + 1][r] = bv.y;
            Bs[c + 2][r] = bv.z;
            Bs[c + 3][r] = bv.w;
        }
        __syncthreads();

#pragma unroll 8
        for (int k = 0; k < 64; ++k) {
            float4 a4 = *(const float4*)&As[k][ty * 4];
            float4 b4 = *(const float4*)&Bs[k][tx * 4];
            float a[4] = {a4.x, a4.y, a4.z, a4.w};
            float b[4] = {b4.x, b4.y, b4.z, b4.w};
#pragma unroll
            for (int i = 0; i < 4; ++i)
#pragma unroll
                for (int j = 0; j < 4; ++j)
                    acc[i][j] = fmaf(a[i], b[j], acc[i][j]);
        }
        __syncthreads();
    }

#pragma unroll
    for (int i = 0; i < 4; ++i) {
        float4 v;
        v.x = acc[i][0]; v.y = acc[i][1]; v.z = acc[i][2]; v.w = acc[i][3];
        *(float4*)(C + (size_t)(bm + ty * 4 + i) * N + bn + tx * 4) = v;
    }
}

// branchless value-only sorted top-4 insert: 7 min/max ops
#define TOP4V_INSERT(mv)                                           \
    do {                                                           \
        float _x  = (mv);                                          \
        float _n0 = fminf(b0, _x);  float _y0 = fmaxf(b0, _x); b0 = _n0; \
        float _n1 = fminf(b1, _y0); float _y1 = fmaxf(b1, _y0); b1 = _n1; \
        float _n2 = fminf(b2, _y1); float _y2 = fmaxf(b2, _y1); b2 = _n2; \
        b3 = fminf(b3, _y2);                                       \
    } while (0)

// stable (dd, j) insert into sorted top-3 (d0<=d1<=d2v), idx tiebreak
#define TOP3JD_INSERT(dd, j)                                       \
    do {                                                           \
        bool lt2 = ((dd) < d2v) || ((dd) == d2v && (j) < j2);      \
        if (lt2) {                                                 \
            bool lt1 = ((dd) < d1) || ((dd) == d1 && (j) < j1);    \
            if (lt1) {                                             \
                d2v = d1; j2 = j1;                                 \
                bool lt0 = ((dd) < d0) || ((dd) == d0 && (j) < j0);\
                if (lt0) { d1 = d0; j1 = j0; d0 = (dd); j0 = (j); }\
                else     { d1 = (dd); j1 = (j); }                  \
            } else { d2v = (dd); j2 = (j); }                       \
        }                                                          \
    } while (0)

// exact reference-f32 d2 of pack point p vs query (sqx,sqy,sqz) with qsq
#define REF_D2(p)                                                              \
    __fsub_rn(__fadd_rn(qsq, __fadd_rn(__fadd_rn(__fmul_rn((p).x, (p).x),      \
                                                 __fmul_rn((p).y, (p).y)),     \
                                       __fmul_rn((p).z, (p).z))),              \
              __fmul_rn(2.0f, __fmaf_rn(sqz, (p).z,                            \
                                __fmaf_rn(sqy, (p).y, __fmul_rn(sqx, (p).x)))))

// Block: 512 threads = 8 waves, owns 64 fine points (lane=query).
// Pass h stages global [h*4096,(h+1)*4096) pair-interleaved in LDS; wave w
// scans its 512-pt slab-local range per pass.
__global__ __launch_bounds__(512) void knn_gather(const float* __restrict__ xyz1,
                                                  const float4* __restrict__ pack,
                                                  const float4* __restrict__ G4,    // [N2*64]
                                                  const float4* __restrict__ bias4, // [64]
                                                  float4* __restrict__ out4,        // [N1*64]
                                                  int N2) {
    // 65536 B: half cloud, pair-interleaved: record 2r={x,x',y,y'}, 2r+1=
    // {z,z',w,w'} for pts {2r,2r+1}. Stage A reuses first 12800 B as mdl/mil.
    __shared__ __align__(16) unsigned char slab_raw[65536];
    // 14464 B: rings [64][RROW] u16; phase 1 reuses as mdl4[64][33] f32;
    // stage B reuses as swgt[64][3] f32 + sidx[64][3] i32.
    __shared__ __align__(16) unsigned char ring_raw[64 * RROW * 2];
    __shared__ float         thr[64];
    __shared__ unsigned char cnts[64][8];

    float4*         slab = (float4*)slab_raw;                    // [4096] records
    float*          mdl  = (float*)slab_raw;                     // [64][25]
    int*            mil  = (int*)(slab_raw + 6400);              // [64][25]
    unsigned short* ring = (unsigned short*)ring_raw;            // [64][RROW]
    float*          mdl4 = (float*)ring_raw;                     // [64][33]
    float*          swgt = (float*)ring_raw;                     // [64][3]
    int*            sidx = (int*)(ring_raw + 768);               // [64][3]

    const int tid  = threadIdx.x;
    const int wave = __builtin_amdgcn_readfirstlane(tid >> 6);
    const int lane = tid & 63;
    const int fine = blockIdx.x * 64 + lane;

    const float qx = xyz1[3 * fine + 0];
    const float qy = xyz1[3 * fine + 1];
    const float qz = xyz1[3 * fine + 2];
    const v2f qx2 = {qx, qx}, qy2 = {qy, qy}, qz2 = {qz, qz};
    const v2f nqx2 = {-qx, -qx}, nqy2 = {-qy, -qy}, nqz2 = {-qz, -qz};

    // ---- Stage half 0 (pair-interleave transpose in registers) ----
#pragma unroll
    for (int i = 0; i < 4; ++i) {
        int pr = i * 512 + tid;                // pair index within half
        float4 p0 = pack[2 * pr + 0];
        float4 p1 = pack[2 * pr + 1];
        float4 A; A.x = p0.x; A.y = p1.x; A.z = p0.y; A.w = p1.y;
        float4 B; B.x = p0.z; B.y = p1.z; B.z = p0.w; B.w = p1.w;
        slab[2 * pr + 0] = A;
        slab[2 * pr + 1] = B;
    }
    __syncthreads();

    // ---- Phase 1: packed m over first 256 pts (128 pairs) of wave range ----
    {
        float b0 = FLT_BIG, b1 = FLT_BIG, b2 = FLT_BIG, b3 = FLT_BIG;
        const float4* sp = slab + wave * 512;  // 256 pair-records = 512 float4
#pragma unroll 1
        for (int k = 0; k < 128; k += 2) {     // 2 pairs = 4 pts per iter
            float4 A0 = sp[2 * k + 0];
            float4 B0 = sp[2 * k + 1];
            float4 A1 = sp[2 * k + 2];
            float4 B1 = sp[2 * k + 3];
            // m = pw - q.p  (3 pk_fma per 2 pts, seed = packed pw)
            v2f m0 = __builtin_elementwise_fma((v2f){A0.x, A0.y}, nqx2,
                     __builtin_elementwise_fma((v2f){A0.z, A0.w}, nqy2,
                     __builtin_elementwise_fma((v2f){B0.x, B0.y}, nqz2,
                                               (v2f){B0.z, B0.w})));
            v2f m1 = __builtin_elementwise_fma((v2f){A1.x, A1.y}, nqx2,
                     __builtin_elementwise_fma((v2f){A1.z, A1.w}, nqy2,
                     __builtin_elementwise_fma((v2f){B1.x, B1.y}, nqz2,
                                               (v2f){B1.z, B1.w})));
            v2f mm2 = __builtin_elementwise_min(m0, m1);
            float mm = fminf(mm2.x, mm2.y);     // batch-min: under-maintains ->
            TOP4V_INSERT(mm);                   // larger t (safe direction)
        }
        mdl4[lane * 33 + wave * 4 + 0] = b0;
        mdl4[lane * 33 + wave * 4 + 1] = b1;
        mdl4[lane * 33 + wave * 4 + 2] = b2;
        mdl4[lane * 33 + wave * 4 + 3] = b3;
    }
    __syncthreads();

    if (tid < 64) {
        float b0 = FLT_BIG, b1 = FLT_BIG, b2 = FLT_BIG, b3 = FLT_BIG;
#pragma unroll
        for (int w = 0; w < 8; ++w)
#pragma unroll
            for (int k = 0; k < 4; ++k)
                TOP4V_INSERT(mdl4[tid * 33 + w * 4 + k]);
        thr[tid] = b3 + MARGIN;   // sample-4th >= true-3rd; margin covers
    }                              // formula-rounding differences vs ref d2
    __syncthreads();

    // ---- Phase 2: two half-passes; packed filter acc = dot+t >= pw ----
    {
        const float t = thr[lane];
        const v2f   T2 = {t, t};
        unsigned short* myring = ring + lane * RROW + wave * CAP;
        int cnt = 0;                            // persists across passes
#pragma unroll 1
        for (int h = 0; h < 2; ++h) {
            if (h == 1) {                       // re-stage second half
                __syncthreads();                // everyone done with half 0
#pragma unroll
                for (int i = 0; i < 4; ++i) {
                    int pr = i * 512 + tid;
                    float4 p0 = pack[4096 + 2 * pr + 0];
                    float4 p1 = pack[4096 + 2 * pr + 1];
                    float4 A; A.x = p0.x; A.y = p1.x; A.z = p0.y; A.w = p1.y;
                    float4 B; B.x = p0.z; B.y = p1.z; B.z = p0.w; B.w = p1.w;
                    slab[2 * pr + 0] = A;
                    slab[2 * pr + 1] = B;
                }
                __syncthreads();
            }
            const float4* sp = slab + wave * 512;
            const int gbase = h * 4096 + wave * 512;   // global pt base
#pragma unroll 2
            for (int jl = 0; jl < 256; jl += 2) {      // 2 pairs = 4 pts
                float4 A0 = sp[2 * jl + 0];
                float4 B0 = sp[2 * jl + 1];
                float4 A1 = sp[2 * jl + 2];
                float4 B1 = sp[2 * jl + 3];
                v2f a0 = __builtin_elementwise_fma((v2f){A0.x, A0.y}, qx2,
                         __builtin_elementwise_fma((v2f){A0.z, A0.w}, qy2,
                         __builtin_elementwise_fma((v2f){B0.x, B0.y}, qz2, T2)));
                v2f a1 = __builtin_elementwise_fma((v2f){A1.x, A1.y}, qx2,
                         __builtin_elementwise_fma((v2f){A1.z, A1.w}, qy2,
                         __builtin_elementwise_fma((v2f){B1.x, B1.y}, qz2, T2)));
                bool s0 = a0.x >= B0.z;
                bool s1 = a0.y >= B0.w;
                bool s2 = a1.x >= B1.z;
                bool s3 = a1.y >= B1.w;
                if (__any(s0 | s1 | s2 | s3)) {        // rare-ish
                    int gp = gbase + 2 * jl;
                    if (s0) { myring[min(cnt, CAP - 1)] = (unsigned short)(gp + 0); ++cnt; }
                    if (s1) { myring[min(cnt, CAP - 1)] = (unsigned short)(gp + 1); ++cnt; }
                    if (s2) { myring[min(cnt, CAP - 1)] = (unsigned short)(gp + 2); ++cnt; }
                    if (s3) { myring[min(cnt, CAP - 1)] = (unsigned short)(gp + 3); ++cnt; }
                }
            }
        }
        cnts[lane][wave] = (unsigned char)min(cnt, 255);   // RAW (overflow flag)
    }
    __syncthreads();

    // ---- Selection stage A: thread (q,w) exact ref-f32 re-score.
    //      Ring complete: score ring. Overflow: exact rescan of the cell's
    //      two 512-pt global ranges (slab is dead / aliased by mdl/mil). ----
    {
        const int q  = tid >> 3;
        const int w  = tid & 7;
        const int fq = blockIdx.x * 64 + q;
        const float sqx = xyz1[3 * fq + 0];
        const float sqy = xyz1[3 * fq + 1];
        const float sqz = xyz1[3 * fq + 2];
        // q_sq = (qx*qx + qy*qy) + qz*qz  (no contraction, ref rounding)
        const float qsq = __fadd_rn(__fadd_rn(__fmul_rn(sqx, sqx), __fmul_rn(sqy, sqy)),
                                    __fmul_rn(sqz, sqz));
        float d0 = FLT_BIG, d1 = FLT_BIG, d2v = FLT_BIG;
        int   j0 = 0x7fffffff, j1 = 0x7fffffff, j2 = 0x7fffffff;
        const int rawn = (int)cnts[q][w];
        if (rawn <= CAP) {
#pragma unroll 1
            for (int e = 0; e < rawn; ++e) {
                const int j = ring[q * RROW + w * CAP + e];
                float4 p = pack[j];             // global; pack is L2-resident
                float dd = REF_D2(p);
                TOP3JD_INSERT(dd, j);
            }
        } else {
            // rare exact fallback: cell = two 512-pt ranges
#pragma unroll 1
            for (int h = 0; h < 2; ++h) {
                const int gb = h * 4096 + w * 512;
#pragma unroll 1
                for (int j = gb; j < gb + 512; ++j) {
                    float4 p = pack[j];
                    float dd = REF_D2(p);
                    TOP3JD_INSERT(dd, j);
                }
            }
        }
        mdl[q * 25 + w * 3 + 0] = d0;  mdl[q * 25 + w * 3 + 1] = d1;  mdl[q * 25 + w * 3 + 2] = d2v;
        mil[q * 25 + w * 3 + 0] = j0;  mil[q * 25 + w * 3 + 1] = j1;  mil[q * 25 + w * 3 + 2] = j2;
    }
    __syncthreads();

    // ---- Selection stage B: one thread per query merges 8x3, weights ----
    // (swgt/sidx alias ring_raw — ring is dead after stage A)
    if (tid < 64) {
        float d0 = FLT_BIG, d1 = FLT_BIG, d2v = FLT_BIG;
        int   j0 = 0x7fffffff, j1 = 0x7fffffff, j2 = 0x7fffffff;
#pragma unroll
        for (int w = 0; w < 8; ++w)
#pragma unroll
            for (int k = 0; k < 3; ++k) {
                float dd = mdl[tid * 25 + w * 3 + k];
                int   j  = mil[tid * 25 + w * 3 + k];
                TOP3JD_INSERT(dd, j);
            }
        // f32 inverse-distance weights, reference op order
        float w0 = 1.0f / (__fadd_rn(sqrtf(fmaxf(d0,  1e-12f)), 1e-8f));
        float w1 = 1.0f / (__fadd_rn(sqrtf(fmaxf(d1,  1e-12f)), 1e-8f));
        float w2 = 1.0f / (__fadd_rn(sqrtf(fmaxf(d2v, 1e-12f)), 1e-8f));
        float wsum = __fadd_rn(__fadd_rn(w0, w1), w2);
        swgt[tid * 3 + 0] = w0 / wsum; sidx[tid * 3 + 0] = j0;
        swgt[tid * 3 + 1] = w1 / wsum; sidx[tid * 3 + 1] = j1;
        swgt[tid * 3 + 2] = w2 / wsum; sidx[tid * 3 + 2] = j2;
    }
    __syncthreads();

    // ---- Gather: out[fine] = w0*G[j0] + w1*G[j1] + w2*G[j2] + b ----
    const float4 bb = bias4[lane];
#pragma unroll
    for (int p = 0; p < 8; ++p) {
        int fl = wave * 8 + p;
        float w0 = swgt[fl * 3 + 0];
        float w1 = swgt[fl * 3 + 1];
        float w2 = swgt[fl * 3 + 2];
        int j0 = sidx[fl * 3 + 0];
        int j1 = sidx[fl * 3 + 1];
        int j2 = sidx[fl * 3 + 2];
        float4 g0 = G4[(size_t)j0 * 64 + lane];
        float4 g1 = G4[(size_t)j1 * 64 + lane];
        float4 g2 = G4[(size_t)j2 * 64 + lane];
        float4 o;
        o.x = fmaf(w0, g0.x, fmaf(w1, g1.x, fmaf(w2, g2.x, bb.x)));
        o.y = fmaf(w0, g0.y, fmaf(w1, g1.y, fmaf(w2, g2.y, bb.y)));
        o.z = fmaf(w0, g0.z, fmaf(w1, g1.z, fmaf(w2, g2.z, bb.z)));
        o.w = fmaf(w0, g0.w, fmaf(w1, g1.w, fmaf(w2, g2.w, bb.w)));
        out4[(size_t)(blockIdx.x * 64 + fl) * 64 + lane] = o;
    }
}

extern "C" void kernel_launch(void* const* d_in, const int* in_sizes, int n_in,
                              void* d_out, int out_size, void* d_ws, size_t ws_size,
                              hipStream_t stream) {
    const float* xyz1 = (const float*)d_in[0];
    const float* xyz2 = (const float*)d_in[1];
    // d_in[2] = feature1 (unused by the reference computation)
    const float* f2   = (const float*)d_in[3];
    const float* W    = (const float*)d_in[6];
    const float* bias = (const float*)d_in[7];

    const int N1  = in_sizes[0] / 3;   // 32768
    const int N2  = in_sizes[1] / 3;   // 8192
    const int C   = in_sizes[3] / N2;  // 256
    const int OUT = in_sizes[7];       // 256

    float*  G    = (float*)d_ws;                                   // N2*OUT f32 = 8 MB
    float4* pack = (float4*)((char*)d_ws + (size_t)N2 * OUT * 4);  // N2 float4 = 128 KB

    prep_kernel<<<(N2 + 255) / 256, 256, 0, stream>>>(xyz2, pack, N2);

    dim3 ggrid(N2 / 64, OUT / 64);
    gemm_nt_f32<<<ggrid, 256, 0, stream>>>(f2, W, G, N2, OUT, C);

    knn_gather<<<N1 / 64, 512, 0, stream>>>(xyz1, pack, (const float4*)G,
                                            (const float4*)bias, (float4*)d_out, N2);
}